// Round 5
// baseline (569.431 us; speedup 1.0000x reference)
//
#include <hip/hip_runtime.h>
#include <stdint.h>

typedef __attribute__((ext_vector_type(4))) float f32x4;
typedef __attribute__((ext_vector_type(8))) __bf16 bf16x8;
typedef __attribute__((ext_vector_type(4))) __bf16 bf16x4;
typedef __attribute__((ext_vector_type(4))) short s16x4;
typedef __attribute__((ext_vector_type(2))) uint32_t u32x2;

#define MFMA16(a, b, c) __builtin_amdgcn_mfma_f32_16x16x32_bf16(a, b, c, 0, 0, 0)
#define MFMA16K16(a, b, c) __builtin_amdgcn_mfma_f32_16x16x16bf16_1k(a, b, c, 0, 0, 0)

#define B_ 4
#define S_ 2048
#define D_ 1024
#define H_ 16
#define NEG_ -1e10f
#define QSCALE 0.180336880f   // 0.125 * log2(e): softmax computed in exp2 domain

// direct v_exp_f32 (D = 2^S0); __exp2f collides with glibc math.h on this toolchain
__device__ __forceinline__ float ex2(float x) { return __builtin_amdgcn_exp2f(x); }

__device__ __forceinline__ void glds16(const void* gsrc, void* ldst) {
  __builtin_amdgcn_global_load_lds(
      (__attribute__((address_space(1))) void*)(gsrc),
      (__attribute__((address_space(3))) void*)(ldst),
      16, 0, 0);
}

__device__ __forceinline__ uint32_t pack_bf16(float a, float b) {
  uint32_t ua = (uint32_t)__builtin_bit_cast(unsigned short, (__bf16)a);
  uint32_t ub = (uint32_t)__builtin_bit_cast(unsigned short, (__bf16)b);
  return ua | (ub << 16);
}

// ---------------- prep: all fp32->bf16 converts + mask pack, one launch ----------------
__global__ __launch_bounds__(256) void prep(
    const float* __restrict__ xq, const float* __restrict__ xk, const float* __restrict__ xv,
    const float* __restrict__ wq, const float* __restrict__ wk, const float* __restrict__ wv,
    const float* __restrict__ wo,
    __bf16* __restrict__ oxq, __bf16* __restrict__ oxk, __bf16* __restrict__ oxv,
    __bf16* __restrict__ owq, __bf16* __restrict__ owk, __bf16* __restrict__ owv,
    __bf16* __restrict__ owo,
    const int* __restrict__ mask, uint32_t* __restrict__ bits, int* __restrict__ flags) {
  int bid = blockIdx.x, tid = threadIdx.x;
  __shared__ int andred;
  if (bid < 24576) {  // X converts: 3 tensors x 8192 blocks x 1024 elems
    int z = bid >> 13, xb = bid & 8191;
    const float* in = (z == 0) ? xq : (z == 1) ? xk : xv;
    __bf16* out = (z == 0) ? oxq : (z == 1) ? oxk : oxv;
    int i = (xb * 256 + tid) * 4;
    float4 v = *(const float4*)(in + i);
    bf16x4 o;
    o.x = (__bf16)v.x; o.y = (__bf16)v.y; o.z = (__bf16)v.z; o.w = (__bf16)v.w;
    *(bf16x4*)(out + i) = o;
  } else if (bid < 28672) {  // W converts: 4 tensors x 1024 blocks
    int m = bid - 24576;
    int z = m >> 10, wb = m & 1023;
    const float* in = (z == 0) ? wq : (z == 1) ? wk : (z == 2) ? wv : wo;
    __bf16* out = (z == 0) ? owq : (z == 1) ? owk : (z == 2) ? owv : owo;
    int i = (wb * 256 + tid) * 4;
    float4 v = *(const float4*)(in + i);
    bf16x4 o;
    o.x = (__bf16)v.x; o.y = (__bf16)v.y; o.z = (__bf16)v.z; o.w = (__bf16)v.w;
    *(bf16x4*)(out + i) = o;
  } else {  // mask pack: 1024 blocks, tile 128x128
    int m = bid - 28672;
    int tt = m & 15, st = (m >> 4) & 15, b = m >> 8;
    int w = tid >> 6, lane = tid & 63;
    if (tid == 0) andred = 1;
    __syncthreads();
    unsigned long long all1 = ~0ull;
    for (int rr = 0; rr < 32; rr++) {
      int srow = st * 128 + w * 32 + rr;
      #pragma unroll
      for (int half = 0; half < 2; half++) {
        int c = tt * 128 + half * 64 + lane;
        int mm = mask[((size_t)b * S_ + srow) * S_ + c];
        unsigned long long bal = __ballot(mm != 0);
        all1 &= bal;
        if (lane == 0) {
          uint32_t* dst = &bits[((size_t)b * S_ + srow) * 64 + tt * 4 + half * 2];
          dst[0] = (uint32_t)bal;
          dst[1] = (uint32_t)(bal >> 32);
        }
      }
    }
    if (all1 != ~0ull) atomicAnd(&andred, 0);
    __syncthreads();
    if (tid == 0) flags[(b * 16 + st) * 16 + tt] = andred;
  }
}

// ---------------- GEMM: acc[i][j] = dot(PA_row, PB_row), K=1024, BK=64 swizzled ----------------
// MODE 0: z=0 q: PA=Wq PB=Xq -> qp [B,H,S,64] *QSCALE ; z=1 k likewise -> kp ;
//         z=2 v: PA=Xv PB=Wv -> vT [B,H,64,S]. All packed bf16x4 stores.
// MODE 1: PA=Wo PB=aout -> f32 out row-major [M,1024], float4 stores
template <int MODE>
__global__ __launch_bounds__(256, 2) void gemm_bt(
    const __bf16* __restrict__ A0, const __bf16* __restrict__ A1, const __bf16* __restrict__ A2,
    const __bf16* __restrict__ W0, const __bf16* __restrict__ W1, const __bf16* __restrict__ W2,
    void* O0, void* O1, void* O2) {
  const int K = 1024;
  const __bf16* PA; const __bf16* PB; void* O;
  int pa_t, pb_t;
  if (MODE == 0) {
    if (blockIdx.z == 0)      { PA = W0; PB = A0; O = O0; pa_t = blockIdx.x; pb_t = blockIdx.y; }
    else if (blockIdx.z == 1) { PA = W1; PB = A1; O = O1; pa_t = blockIdx.x; pb_t = blockIdx.y; }
    else                      { PA = A2; PB = W2; O = O2; pa_t = blockIdx.y; pb_t = blockIdx.x; }
  } else { PA = W0; PB = A0; O = O0; pa_t = blockIdx.x; pb_t = blockIdx.y; }

  __shared__ __align__(16) __bf16 As[128 * 64];
  __shared__ __align__(16) __bf16 Bs[128 * 64];
  int tid = threadIdx.x, lane = tid & 63, w = tid >> 6;
  int wm = w >> 1, wn = w & 1;
  int g = lane >> 4, l15 = lane & 15;
  f32x4 acc[4][4] = {};
  const __bf16* Ablk = PA + (size_t)(pa_t * 128) * K;
  const __bf16* Bblk = PB + (size_t)(pb_t * 128) * K;

  for (int kt = 0; kt < K; kt += 64) {
    __syncthreads();
    #pragma unroll
    for (int r = 0; r < 4; r++) {
      int C = r * 256 + tid;
      int row = C >> 3, c = C & 7;
      int c0 = c ^ (row & 7);
      glds16(Ablk + (size_t)row * K + kt + c0 * 8, (char*)As + C * 16);
      glds16(Bblk + (size_t)row * K + kt + c0 * 8, (char*)Bs + C * 16);
    }
    __syncthreads();
    #pragma unroll
    for (int kkq = 0; kkq < 2; kkq++) {
      bf16x8 af[4], bfr[4];
      #pragma unroll
      for (int i = 0; i < 4; i++) {
        int row = wm * 64 + i * 16 + l15;
        int ch = (kkq * 4 + g) ^ (row & 7);
        af[i] = *(const bf16x8*)((const char*)As + row * 128 + ch * 16);
      }
      #pragma unroll
      for (int j = 0; j < 4; j++) {
        int row = wn * 64 + j * 16 + l15;
        int ch = (kkq * 4 + g) ^ (row & 7);
        bfr[j] = *(const bf16x8*)((const char*)Bs + row * 128 + ch * 16);
      }
      #pragma unroll
      for (int i = 0; i < 4; i++)
        #pragma unroll
        for (int j = 0; j < 4; j++)
          acc[i][j] = MFMA16(af[i], bfr[j], acc[i][j]);
    }
  }

  if (MODE == 1) {
    // n = PA(Wo) rows (g*4+r contiguous), m = PB(aout) rows -> float4 stores
    #pragma unroll
    for (int i = 0; i < 4; i++)
      #pragma unroll
      for (int j = 0; j < 4; j++) {
        int n0 = pa_t * 128 + wm * 64 + i * 16 + g * 4;
        int m = pb_t * 128 + wn * 64 + j * 16 + l15;
        *(f32x4*)((float*)O + (size_t)m * 1024 + n0) = acc[i][j];
      }
  } else if (blockIdx.z == 2) {
    // v -> vT [B,H,64,S]; rows of PA are s, rows of PB are dv
    #pragma unroll
    for (int i = 0; i < 4; i++)
      #pragma unroll
      for (int j = 0; j < 4; j++) {
        int s0 = pa_t * 128 + wm * 64 + i * 16 + g * 4;
        int dvg = pb_t * 128 + wn * 64 + j * 16 + l15;
        int b = s0 >> 11, s = s0 & 2047;
        int h = dvg >> 6, dv = dvg & 63;
        bf16x4 o;
        #pragma unroll
        for (int r = 0; r < 4; r++) o[r] = (__bf16)acc[i][j][r];
        *(bf16x4*)((__bf16*)O + (((size_t)b * 16 + h) * 64 + dv) * 2048 + s) = o;
      }
  } else {
    // q/k -> [B,H,S,64]; rows of PA are dk, rows of PB are s
    float scale = (blockIdx.z == 0) ? QSCALE : 1.0f;
    #pragma unroll
    for (int i = 0; i < 4; i++)
      #pragma unroll
      for (int j = 0; j < 4; j++) {
        int dkg = pa_t * 128 + wm * 64 + i * 16 + g * 4;
        int sg = pb_t * 128 + wn * 64 + j * 16 + l15;
        int h = dkg >> 6, dk = dkg & 63;
        int b = sg >> 11, s = sg & 2047;
        bf16x4 o;
        #pragma unroll
        for (int r = 0; r < 4; r++) o[r] = (__bf16)(acc[i][j][r] * scale);
        *(bf16x4*)((__bf16*)O + (((size_t)b * 16 + h) * 2048 + s) * 64 + dk) = o;
      }
  }
}

// ---------------- flash attention (S^T formulation, exp2 domain, K=16 MFMA PV) ----------------
__global__ __launch_bounds__(256, 3) void attn(
    const __bf16* __restrict__ qp, const __bf16* __restrict__ kp,
    const __bf16* __restrict__ vt_, __bf16* __restrict__ aout,
    const uint32_t* __restrict__ bits, const int* __restrict__ flags) {
  int qt = blockIdx.x, bh = blockIdx.y, b = bh >> 4, h = bh & 15;
  int tid = threadIdx.x, lane = tid & 63, w = tid >> 6;
  int g = lane >> 4, l15 = lane & 15;

  __shared__ __align__(16) char smem[32768];
  char* Klds = smem;            // [128 kcol][64 dk] bf16, chunk-swizzled
  char* Vlds = smem + 16384;    // [64 dv][128 kcol] bf16, chunk-swizzled

  const __bf16* Qg = qp + ((size_t)bh * S_ + qt * 128) * 64;
  const __bf16* Kg = kp + (size_t)bh * S_ * 64;
  const __bf16* Vg = vt_ + (size_t)bh * 64 * S_;

  // stage Q (swizzled [128][64]) into Klds region, pull B-operand frags
  #pragma unroll
  for (int r = 0; r < 4; r++) {
    int C = r * 256 + tid;
    int row = C >> 3, c = C & 7, c0 = c ^ (row & 7);
    glds16(Qg + row * 64 + c0 * 8, Klds + C * 16);
  }
  __syncthreads();
  bf16x8 qf[2][2];  // Q[qrow=w*32+i*16+l15][dk=kkq*32+g*8+j]
  #pragma unroll
  for (int i = 0; i < 2; i++)
    #pragma unroll
    for (int kkq = 0; kkq < 2; kkq++) {
      int row = w * 32 + i * 16 + l15;
      int ch = (kkq * 4 + g) ^ (row & 7);
      qf[i][kkq] = *(const bf16x8*)(Klds + row * 128 + ch * 16);
    }
  __syncthreads();

  f32x4 oacc[4][2] = {};  // O^T[dv=vt*16+g*4+r][qrow=w*32+i*16+l15]
  float mst[2] = {-INFINITY, -INFINITY}, lst[2] = {0.f, 0.f};

  for (int kt = 0; kt < 16; kt++) {
    const __bf16* Ks = Kg + (size_t)kt * 128 * 64;
    #pragma unroll
    for (int r = 0; r < 4; r++) {
      int C = r * 256 + tid;
      int row = C >> 3, c = C & 7, c0 = c ^ (row & 7);
      glds16(Ks + row * 64 + c0 * 8, Klds + C * 16);
    }
    #pragma unroll
    for (int r = 0; r < 4; r++) {
      int C = r * 256 + tid;
      int row = C >> 4, c = C & 15;
      int c0 = (c & 8) | ((c & 7) ^ (row & 7));
      glds16(Vg + (size_t)row * S_ + kt * 128 + c0 * 8, Vlds + C * 16);
    }
    __syncthreads();

    // S^T = K * Q^T ; sacc[i][jt]: kcol=jt*16+g*4+r, qrow=w*32+i*16+l15
    f32x4 sacc[2][8] = {};
    #pragma unroll
    for (int jt = 0; jt < 8; jt++) {
      int row = jt * 16 + l15;
      bf16x8 kf0 = *(const bf16x8*)(Klds + row * 128 + (g ^ (row & 7)) * 16);
      bf16x8 kf1 = *(const bf16x8*)(Klds + row * 128 + ((4 + g) ^ (row & 7)) * 16);
      sacc[0][jt] = MFMA16(kf0, qf[0][0], sacc[0][jt]);
      sacc[0][jt] = MFMA16(kf1, qf[0][1], sacc[0][jt]);
      sacc[1][jt] = MFMA16(kf0, qf[1][0], sacc[1][jt]);
      sacc[1][jt] = MFMA16(kf1, qf[1][1], sacc[1][jt]);
    }

    if (!flags[(b * 16 + qt) * 16 + kt]) {  // exact masking slow path
      #pragma unroll
      for (int i = 0; i < 2; i++) {
        int srow = qt * 128 + w * 32 + i * 16 + l15;
        const uint32_t* bw = &bits[((size_t)b * S_ + srow) * 64 + kt * 4];
        uint32_t mw[4] = {bw[0], bw[1], bw[2], bw[3]};
        #pragma unroll
        for (int jt = 0; jt < 8; jt++)
          #pragma unroll
          for (int r = 0; r < 4; r++) {
            int bitpos = (jt & 1) * 16 + g * 4 + r;
            if (!((mw[jt >> 1] >> bitpos) & 1)) sacc[i][jt][r] = NEG_;
          }
      }
    }

    // row max (exp2 domain) + rescale
    float alpha[2];
    #pragma unroll
    for (int i = 0; i < 2; i++) {
      float mx = -INFINITY;
      #pragma unroll
      for (int jt = 0; jt < 8; jt++)
        #pragma unroll
        for (int r = 0; r < 4; r++) mx = fmaxf(mx, sacc[i][jt][r]);
      mx = fmaxf(mx, __shfl_xor(mx, 16));
      mx = fmaxf(mx, __shfl_xor(mx, 32));
      float mnew = fmaxf(mst[i], mx);
      alpha[i] = ex2(mst[i] - mnew);
      mst[i] = mnew;
    }
    #pragma unroll
    for (int vt = 0; vt < 4; vt++)
      #pragma unroll
      for (int i = 0; i < 2; i++)
        #pragma unroll
        for (int r = 0; r < 4; r++) oacc[vt][i][r] *= alpha[i];

    // per 16-col group: exp2 -> pack -> PV MFMA immediately (short pf lifetime)
    float sum[2] = {0.f, 0.f};
    #pragma unroll
    for (int jt = 0; jt < 8; jt++) {
      s16x4 pf[2];
      #pragma unroll
      for (int i = 0; i < 2; i++) {
        float p0 = ex2(sacc[i][jt][0] - mst[i]);
        float p1 = ex2(sacc[i][jt][1] - mst[i]);
        float p2 = ex2(sacc[i][jt][2] - mst[i]);
        float p3 = ex2(sacc[i][jt][3] - mst[i]);
        sum[i] += (p0 + p1) + (p2 + p3);
        u32x2 t;
        t.x = pack_bf16(p0, p1);
        t.y = pack_bf16(p2, p3);
        pf[i] = __builtin_bit_cast(s16x4, t);
      }
      int ch = jt * 2 + (g >> 1);
      #pragma unroll
      for (int vt = 0; vt < 4; vt++) {
        int row = vt * 16 + l15;
        int chs = (ch & 8) | ((ch & 7) ^ (row & 7));
        s16x4 vv = *(const s16x4*)(Vlds + row * 256 + chs * 16 + (g & 1) * 8);
        oacc[vt][0] = MFMA16K16(vv, pf[0], oacc[vt][0]);
        oacc[vt][1] = MFMA16K16(vv, pf[1], oacc[vt][1]);
      }
    }
    #pragma unroll
    for (int i = 0; i < 2; i++) {
      sum[i] += __shfl_xor(sum[i], 16);
      sum[i] += __shfl_xor(sum[i], 32);
      lst[i] = lst[i] * alpha[i] + sum[i];
    }
    __syncthreads();
  }

  // epilogue: O^T / l -> attn_out [B,S,H*64] bf16
  #pragma unroll
  for (int i = 0; i < 2; i++) {
    float inv = 1.0f / lst[i];
    int srow = qt * 128 + w * 32 + i * 16 + l15;
    #pragma unroll
    for (int vt = 0; vt < 4; vt++) {
      bf16x4 o;
      #pragma unroll
      for (int r = 0; r < 4; r++) o[r] = (__bf16)(oacc[vt][i][r] * inv);
      *(bf16x4*)(aout + ((size_t)b * S_ + srow) * 1024 + h * 64 + vt * 16 + g * 4) = o;
    }
  }
}

// ---------------- launch ----------------
extern "C" void kernel_launch(void* const* d_in, const int* in_sizes, int n_in,
                              void* d_out, int out_size, void* d_ws, size_t ws_size,
                              hipStream_t stream) {
  const float* queries = (const float*)d_in[0];
  const float* keys    = (const float*)d_in[1];
  const float* values  = (const float*)d_in[2];
  const int*   mask    = (const int*)d_in[3];
  const float* Wq      = (const float*)d_in[4];
  const float* Wk      = (const float*)d_in[5];
  const float* Wv      = (const float*)d_in[6];
  const float* Wo      = (const float*)d_in[7];

  char* ws = (char*)d_ws;
  __bf16* Xq  = (__bf16*)(ws + 0);          // 16 MB, later reused as attn_out
  __bf16* Xk  = (__bf16*)(ws + 16777216);   // 16 MB
  __bf16* Xv  = (__bf16*)(ws + 33554432);   // 16 MB
  __bf16* Wqb = (__bf16*)(ws + 50331648);   // 2 MB each
  __bf16* Wkb = (__bf16*)(ws + 52428800);
  __bf16* Wvb = (__bf16*)(ws + 54525952);
  __bf16* Wob = (__bf16*)(ws + 56623104);
  __bf16* qp  = (__bf16*)(ws + 58720256);   // 16 MB [B,H,S,64]
  __bf16* kp  = (__bf16*)(ws + 75497472);   // 16 MB [B,H,S,64]
  __bf16* vT  = (__bf16*)(ws + 92274688);   // 16 MB [B,H,64,S]
  uint32_t* bits = (uint32_t*)(ws + 109051904);  // 2 MB
  int* flags     = (int*)(ws + 111149056);       // 4 KB
  __bf16* aout = Xq;  // alias: Xq dead after proj GEMM

  prep<<<29696, 256, 0, stream>>>(queries, keys, values, Wq, Wk, Wv, Wo,
                                  Xq, Xk, Xv, Wqb, Wkb, Wvb, Wob,
                                  mask, bits, flags);

  gemm_bt<0><<<dim3(8, 64, 3), 256, 0, stream>>>(Xq, Xk, Xv, Wqb, Wkb, Wvb,
                                                 (void*)qp, (void*)kp, (void*)vT);

  attn<<<dim3(16, 64), 256, 0, stream>>>(qp, kp, vT, aout, bits, flags);

  gemm_bt<1><<<dim3(8, 64, 1), 256, 0, stream>>>(aout, nullptr, nullptr, Wob, nullptr, nullptr,
                                                 (void*)d_out, nullptr, nullptr);
}

// Round 6
// 431.182 us; speedup vs baseline: 1.3206x; 1.3206x over previous
//
#include <hip/hip_runtime.h>
#include <stdint.h>

typedef __attribute__((ext_vector_type(4))) float f32x4;
typedef __attribute__((ext_vector_type(8))) __bf16 bf16x8;
typedef __attribute__((ext_vector_type(4))) __bf16 bf16x4;
typedef __attribute__((ext_vector_type(4))) short s16x4;
typedef __attribute__((ext_vector_type(2))) uint32_t u32x2;

#define MFMA16(a, b, c) __builtin_amdgcn_mfma_f32_16x16x32_bf16(a, b, c, 0, 0, 0)
#define MFMA16K16(a, b, c) __builtin_amdgcn_mfma_f32_16x16x16bf16_1k(a, b, c, 0, 0, 0)

#define B_ 4
#define S_ 2048
#define D_ 1024
#define H_ 16
#define NEG_ -1e10f
#define QSCALE 0.180336880f   // 0.125 * log2(e): softmax computed in exp2 domain

// direct v_exp_f32 (D = 2^S0); __exp2f collides with glibc math.h on this toolchain
__device__ __forceinline__ float ex2(float x) { return __builtin_amdgcn_exp2f(x); }

__device__ __forceinline__ void glds16(const void* gsrc, void* ldst) {
  __builtin_amdgcn_global_load_lds(
      (__attribute__((address_space(1))) void*)(gsrc),
      (__attribute__((address_space(3))) void*)(ldst),
      16, 0, 0);
}

__device__ __forceinline__ uint32_t pack_bf16(float a, float b) {
  uint32_t ua = (uint32_t)__builtin_bit_cast(unsigned short, (__bf16)a);
  uint32_t ub = (uint32_t)__builtin_bit_cast(unsigned short, (__bf16)b);
  return ua | (ub << 16);
}

// ---------------- prep: all fp32->bf16 converts + mask pack, one launch ----------------
__global__ __launch_bounds__(256) void prep(
    const float* __restrict__ xq, const float* __restrict__ xk, const float* __restrict__ xv,
    const float* __restrict__ wq, const float* __restrict__ wk, const float* __restrict__ wv,
    const float* __restrict__ wo,
    __bf16* __restrict__ oxq, __bf16* __restrict__ oxk, __bf16* __restrict__ oxv,
    __bf16* __restrict__ owq, __bf16* __restrict__ owk, __bf16* __restrict__ owv,
    __bf16* __restrict__ owo,
    const int* __restrict__ mask, uint32_t* __restrict__ bits, int* __restrict__ flags) {
  int bid = blockIdx.x, tid = threadIdx.x;
  __shared__ int andred;
  if (bid < 24576) {  // X converts: 3 tensors x 8192 blocks x 1024 elems
    int z = bid >> 13, xb = bid & 8191;
    const float* in = (z == 0) ? xq : (z == 1) ? xk : xv;
    __bf16* out = (z == 0) ? oxq : (z == 1) ? oxk : oxv;
    int i = (xb * 256 + tid) * 4;
    float4 v = *(const float4*)(in + i);
    bf16x4 o;
    o.x = (__bf16)v.x; o.y = (__bf16)v.y; o.z = (__bf16)v.z; o.w = (__bf16)v.w;
    *(bf16x4*)(out + i) = o;
  } else if (bid < 28672) {  // W converts: 4 tensors x 1024 blocks
    int m = bid - 24576;
    int z = m >> 10, wb = m & 1023;
    const float* in = (z == 0) ? wq : (z == 1) ? wk : (z == 2) ? wv : wo;
    __bf16* out = (z == 0) ? owq : (z == 1) ? owk : (z == 2) ? owv : owo;
    int i = (wb * 256 + tid) * 4;
    float4 v = *(const float4*)(in + i);
    bf16x4 o;
    o.x = (__bf16)v.x; o.y = (__bf16)v.y; o.z = (__bf16)v.z; o.w = (__bf16)v.w;
    *(bf16x4*)(out + i) = o;
  } else {  // mask pack: 1024 blocks, tile 128x128
    int m = bid - 28672;
    int tt = m & 15, st = (m >> 4) & 15, b = m >> 8;
    int w = tid >> 6, lane = tid & 63;
    if (tid == 0) andred = 1;
    __syncthreads();
    unsigned long long all1 = ~0ull;
    for (int rr = 0; rr < 32; rr++) {
      int srow = st * 128 + w * 32 + rr;
      #pragma unroll
      for (int half = 0; half < 2; half++) {
        int c = tt * 128 + half * 64 + lane;
        int mm = mask[((size_t)b * S_ + srow) * S_ + c];
        unsigned long long bal = __ballot(mm != 0);
        all1 &= bal;
        if (lane == 0) {
          uint32_t* dst = &bits[((size_t)b * S_ + srow) * 64 + tt * 4 + half * 2];
          dst[0] = (uint32_t)bal;
          dst[1] = (uint32_t)(bal >> 32);
        }
      }
    }
    if (all1 != ~0ull) atomicAnd(&andred, 0);
    __syncthreads();
    if (tid == 0) flags[(b * 16 + st) * 16 + tt] = andred;
  }
}

// ---------------- GEMM: acc[i][j] = dot(PA_row, PB_row), K=1024, BK=64 swizzled ----------------
// MODE 0: z=0 q: PA=Wq PB=Xq -> qp [B,H,S,64] *QSCALE ; z=1 k likewise -> kp ;
//         z=2 v: PA=Xv PB=Wv -> vT [B,H,64,S]. All packed bf16x4 stores.
// MODE 1: PA=Wo PB=aout -> f32 out row-major [M,1024], float4 stores
template <int MODE>
__global__ __launch_bounds__(256, 3) void gemm_bt(
    const __bf16* __restrict__ A0, const __bf16* __restrict__ A1, const __bf16* __restrict__ A2,
    const __bf16* __restrict__ W0, const __bf16* __restrict__ W1, const __bf16* __restrict__ W2,
    void* O0, void* O1, void* O2) {
  const int K = 1024;
  const __bf16* PA; const __bf16* PB; void* O;
  int pa_t, pb_t;
  if (MODE == 0) {
    if (blockIdx.z == 0)      { PA = W0; PB = A0; O = O0; pa_t = blockIdx.x; pb_t = blockIdx.y; }
    else if (blockIdx.z == 1) { PA = W1; PB = A1; O = O1; pa_t = blockIdx.x; pb_t = blockIdx.y; }
    else                      { PA = A2; PB = W2; O = O2; pa_t = blockIdx.y; pb_t = blockIdx.x; }
  } else { PA = W0; PB = A0; O = O0; pa_t = blockIdx.x; pb_t = blockIdx.y; }

  __shared__ __align__(16) __bf16 As[128 * 64];
  __shared__ __align__(16) __bf16 Bs[128 * 64];
  int tid = threadIdx.x, lane = tid & 63, w = tid >> 6;
  int wm = w >> 1, wn = w & 1;
  int g = lane >> 4, l15 = lane & 15;
  f32x4 acc[4][4] = {};
  const __bf16* Ablk = PA + (size_t)(pa_t * 128) * K;
  const __bf16* Bblk = PB + (size_t)(pb_t * 128) * K;

  for (int kt = 0; kt < K; kt += 64) {
    __syncthreads();
    #pragma unroll
    for (int r = 0; r < 4; r++) {
      int C = r * 256 + tid;
      int row = C >> 3, c = C & 7;
      int c0 = c ^ (row & 7);
      glds16(Ablk + (size_t)row * K + kt + c0 * 8, (char*)As + C * 16);
      glds16(Bblk + (size_t)row * K + kt + c0 * 8, (char*)Bs + C * 16);
    }
    __syncthreads();
    #pragma unroll
    for (int kkq = 0; kkq < 2; kkq++) {
      bf16x8 af[4], bfr[4];
      #pragma unroll
      for (int i = 0; i < 4; i++) {
        int row = wm * 64 + i * 16 + l15;
        int ch = (kkq * 4 + g) ^ (row & 7);
        af[i] = *(const bf16x8*)((const char*)As + row * 128 + ch * 16);
      }
      #pragma unroll
      for (int j = 0; j < 4; j++) {
        int row = wn * 64 + j * 16 + l15;
        int ch = (kkq * 4 + g) ^ (row & 7);
        bfr[j] = *(const bf16x8*)((const char*)Bs + row * 128 + ch * 16);
      }
      #pragma unroll
      for (int i = 0; i < 4; i++)
        #pragma unroll
        for (int j = 0; j < 4; j++)
          acc[i][j] = MFMA16(af[i], bfr[j], acc[i][j]);
    }
  }

  if (MODE == 1) {
    // n = PA(Wo) rows (g*4+r contiguous), m = PB(aout) rows -> float4 stores
    #pragma unroll
    for (int i = 0; i < 4; i++)
      #pragma unroll
      for (int j = 0; j < 4; j++) {
        int n0 = pa_t * 128 + wm * 64 + i * 16 + g * 4;
        int m = pb_t * 128 + wn * 64 + j * 16 + l15;
        *(f32x4*)((float*)O + (size_t)m * 1024 + n0) = acc[i][j];
      }
  } else if (blockIdx.z == 2) {
    // v -> vT [B,H,64,S]; rows of PA are s, rows of PB are dv
    #pragma unroll
    for (int i = 0; i < 4; i++)
      #pragma unroll
      for (int j = 0; j < 4; j++) {
        int s0 = pa_t * 128 + wm * 64 + i * 16 + g * 4;
        int dvg = pb_t * 128 + wn * 64 + j * 16 + l15;
        int b = s0 >> 11, s = s0 & 2047;
        int h = dvg >> 6, dv = dvg & 63;
        bf16x4 o;
        #pragma unroll
        for (int r = 0; r < 4; r++) o[r] = (__bf16)acc[i][j][r];
        *(bf16x4*)((__bf16*)O + (((size_t)b * 16 + h) * 64 + dv) * 2048 + s) = o;
      }
  } else {
    // q/k -> [B,H,S,64]; rows of PA are dk, rows of PB are s
    float scale = (blockIdx.z == 0) ? QSCALE : 1.0f;
    #pragma unroll
    for (int i = 0; i < 4; i++)
      #pragma unroll
      for (int j = 0; j < 4; j++) {
        int dkg = pa_t * 128 + wm * 64 + i * 16 + g * 4;
        int sg = pb_t * 128 + wn * 64 + j * 16 + l15;
        int h = dkg >> 6, dk = dkg & 63;
        int b = sg >> 11, s = sg & 2047;
        bf16x4 o;
        #pragma unroll
        for (int r = 0; r < 4; r++) o[r] = (__bf16)(acc[i][j][r] * scale);
        *(bf16x4*)((__bf16*)O + (((size_t)b * 16 + h) * 2048 + s) * 64 + dk) = o;
      }
  }
}

// ---------------- flash attention (S^T formulation, exp2 domain, K=16 MFMA PV) ----------------
// launch_bounds (256,2): merged-softmax live set (sacc 64 + oacc 32 + qf 16 + misc)
// needs the 256-reg budget; (256,3) forced a 268 MB/launch scratch spill (round 5).
__global__ __launch_bounds__(256, 2) void attn(
    const __bf16* __restrict__ qp, const __bf16* __restrict__ kp,
    const __bf16* __restrict__ vt_, __bf16* __restrict__ aout,
    const uint32_t* __restrict__ bits, const int* __restrict__ flags) {
  int qt = blockIdx.x, bh = blockIdx.y, b = bh >> 4, h = bh & 15;
  int tid = threadIdx.x, lane = tid & 63, w = tid >> 6;
  int g = lane >> 4, l15 = lane & 15;

  __shared__ __align__(16) char smem[32768];
  char* Klds = smem;            // [128 kcol][64 dk] bf16, chunk-swizzled
  char* Vlds = smem + 16384;    // [64 dv][128 kcol] bf16, chunk-swizzled

  const __bf16* Qg = qp + ((size_t)bh * S_ + qt * 128) * 64;
  const __bf16* Kg = kp + (size_t)bh * S_ * 64;
  const __bf16* Vg = vt_ + (size_t)bh * 64 * S_;

  // stage Q (swizzled [128][64]) into Klds region, pull B-operand frags
  #pragma unroll
  for (int r = 0; r < 4; r++) {
    int C = r * 256 + tid;
    int row = C >> 3, c = C & 7, c0 = c ^ (row & 7);
    glds16(Qg + row * 64 + c0 * 8, Klds + C * 16);
  }
  __syncthreads();
  bf16x8 qf[2][2];  // Q[qrow=w*32+i*16+l15][dk=kkq*32+g*8+j]
  #pragma unroll
  for (int i = 0; i < 2; i++)
    #pragma unroll
    for (int kkq = 0; kkq < 2; kkq++) {
      int row = w * 32 + i * 16 + l15;
      int ch = (kkq * 4 + g) ^ (row & 7);
      qf[i][kkq] = *(const bf16x8*)(Klds + row * 128 + ch * 16);
    }
  __syncthreads();

  f32x4 oacc[4][2] = {};  // O^T[dv=vt*16+g*4+r][qrow=w*32+i*16+l15]
  float mst[2] = {-INFINITY, -INFINITY}, lst[2] = {0.f, 0.f};

  for (int kt = 0; kt < 16; kt++) {
    const __bf16* Ks = Kg + (size_t)kt * 128 * 64;
    #pragma unroll
    for (int r = 0; r < 4; r++) {
      int C = r * 256 + tid;
      int row = C >> 3, c = C & 7, c0 = c ^ (row & 7);
      glds16(Ks + row * 64 + c0 * 8, Klds + C * 16);
    }
    #pragma unroll
    for (int r = 0; r < 4; r++) {
      int C = r * 256 + tid;
      int row = C >> 4, c = C & 15;
      int c0 = (c & 8) | ((c & 7) ^ (row & 7));
      glds16(Vg + (size_t)row * S_ + kt * 128 + c0 * 8, Vlds + C * 16);
    }
    __syncthreads();

    // S^T = K * Q^T ; sacc[i][jt]: kcol=jt*16+g*4+r, qrow=w*32+i*16+l15
    f32x4 sacc[2][8] = {};
    #pragma unroll
    for (int jt = 0; jt < 8; jt++) {
      int row = jt * 16 + l15;
      bf16x8 kf0 = *(const bf16x8*)(Klds + row * 128 + (g ^ (row & 7)) * 16);
      bf16x8 kf1 = *(const bf16x8*)(Klds + row * 128 + ((4 + g) ^ (row & 7)) * 16);
      sacc[0][jt] = MFMA16(kf0, qf[0][0], sacc[0][jt]);
      sacc[0][jt] = MFMA16(kf1, qf[0][1], sacc[0][jt]);
      sacc[1][jt] = MFMA16(kf0, qf[1][0], sacc[1][jt]);
      sacc[1][jt] = MFMA16(kf1, qf[1][1], sacc[1][jt]);
    }

    if (!flags[(b * 16 + qt) * 16 + kt]) {  // exact masking slow path
      #pragma unroll
      for (int i = 0; i < 2; i++) {
        int srow = qt * 128 + w * 32 + i * 16 + l15;
        const uint32_t* bw = &bits[((size_t)b * S_ + srow) * 64 + kt * 4];
        uint32_t mw[4] = {bw[0], bw[1], bw[2], bw[3]};
        #pragma unroll
        for (int jt = 0; jt < 8; jt++)
          #pragma unroll
          for (int r = 0; r < 4; r++) {
            int bitpos = (jt & 1) * 16 + g * 4 + r;
            if (!((mw[jt >> 1] >> bitpos) & 1)) sacc[i][jt][r] = NEG_;
          }
      }
    }

    // row max (exp2 domain) + rescale
    float alpha[2];
    #pragma unroll
    for (int i = 0; i < 2; i++) {
      float mx = -INFINITY;
      #pragma unroll
      for (int jt = 0; jt < 8; jt++)
        #pragma unroll
        for (int r = 0; r < 4; r++) mx = fmaxf(mx, sacc[i][jt][r]);
      mx = fmaxf(mx, __shfl_xor(mx, 16));
      mx = fmaxf(mx, __shfl_xor(mx, 32));
      float mnew = fmaxf(mst[i], mx);
      alpha[i] = ex2(mst[i] - mnew);
      mst[i] = mnew;
    }
    #pragma unroll
    for (int vt = 0; vt < 4; vt++)
      #pragma unroll
      for (int i = 0; i < 2; i++)
        #pragma unroll
        for (int r = 0; r < 4; r++) oacc[vt][i][r] *= alpha[i];

    // per 16-col group: exp2 -> pack -> PV MFMA immediately (short pf lifetime)
    float sum[2] = {0.f, 0.f};
    #pragma unroll
    for (int jt = 0; jt < 8; jt++) {
      s16x4 pf[2];
      #pragma unroll
      for (int i = 0; i < 2; i++) {
        float p0 = ex2(sacc[i][jt][0] - mst[i]);
        float p1 = ex2(sacc[i][jt][1] - mst[i]);
        float p2 = ex2(sacc[i][jt][2] - mst[i]);
        float p3 = ex2(sacc[i][jt][3] - mst[i]);
        sum[i] += (p0 + p1) + (p2 + p3);
        u32x2 t;
        t.x = pack_bf16(p0, p1);
        t.y = pack_bf16(p2, p3);
        pf[i] = __builtin_bit_cast(s16x4, t);
      }
      int ch = jt * 2 + (g >> 1);
      #pragma unroll
      for (int vt = 0; vt < 4; vt++) {
        int row = vt * 16 + l15;
        int chs = (ch & 8) | ((ch & 7) ^ (row & 7));
        s16x4 vv = *(const s16x4*)(Vlds + row * 256 + chs * 16 + (g & 1) * 8);
        oacc[vt][0] = MFMA16K16(vv, pf[0], oacc[vt][0]);
        oacc[vt][1] = MFMA16K16(vv, pf[1], oacc[vt][1]);
      }
    }
    #pragma unroll
    for (int i = 0; i < 2; i++) {
      sum[i] += __shfl_xor(sum[i], 16);
      sum[i] += __shfl_xor(sum[i], 32);
      lst[i] = lst[i] * alpha[i] + sum[i];
    }
    __syncthreads();
  }

  // epilogue: O^T / l -> attn_out [B,S,H*64] bf16
  #pragma unroll
  for (int i = 0; i < 2; i++) {
    float inv = 1.0f / lst[i];
    int srow = qt * 128 + w * 32 + i * 16 + l15;
    #pragma unroll
    for (int vt = 0; vt < 4; vt++) {
      bf16x4 o;
      #pragma unroll
      for (int r = 0; r < 4; r++) o[r] = (__bf16)(oacc[vt][i][r] * inv);
      *(bf16x4*)(aout + ((size_t)b * S_ + srow) * 1024 + h * 64 + vt * 16 + g * 4) = o;
    }
  }
}

// ---------------- launch ----------------
extern "C" void kernel_launch(void* const* d_in, const int* in_sizes, int n_in,
                              void* d_out, int out_size, void* d_ws, size_t ws_size,
                              hipStream_t stream) {
  const float* queries = (const float*)d_in[0];
  const float* keys    = (const float*)d_in[1];
  const float* values  = (const float*)d_in[2];
  const int*   mask    = (const int*)d_in[3];
  const float* Wq      = (const float*)d_in[4];
  const float* Wk      = (const float*)d_in[5];
  const float* Wv      = (const float*)d_in[6];
  const float* Wo      = (const float*)d_in[7];

  char* ws = (char*)d_ws;
  __bf16* Xq  = (__bf16*)(ws + 0);          // 16 MB, later reused as attn_out
  __bf16* Xk  = (__bf16*)(ws + 16777216);   // 16 MB
  __bf16* Xv  = (__bf16*)(ws + 33554432);   // 16 MB
  __bf16* Wqb = (__bf16*)(ws + 50331648);   // 2 MB each
  __bf16* Wkb = (__bf16*)(ws + 52428800);
  __bf16* Wvb = (__bf16*)(ws + 54525952);
  __bf16* Wob = (__bf16*)(ws + 56623104);
  __bf16* qp  = (__bf16*)(ws + 58720256);   // 16 MB [B,H,S,64]
  __bf16* kp  = (__bf16*)(ws + 75497472);   // 16 MB [B,H,S,64]
  __bf16* vT  = (__bf16*)(ws + 92274688);   // 16 MB [B,H,64,S]
  uint32_t* bits = (uint32_t*)(ws + 109051904);  // 2 MB
  int* flags     = (int*)(ws + 111149056);       // 4 KB
  __bf16* aout = Xq;  // alias: Xq dead after proj GEMM

  prep<<<29696, 256, 0, stream>>>(queries, keys, values, Wq, Wk, Wv, Wo,
                                  Xq, Xk, Xv, Wqb, Wkb, Wvb, Wob,
                                  mask, bits, flags);

  gemm_bt<0><<<dim3(8, 64, 3), 256, 0, stream>>>(Xq, Xk, Xv, Wqb, Wkb, Wvb,
                                                 (void*)qp, (void*)kp, (void*)vT);

  attn<<<dim3(16, 64), 256, 0, stream>>>(qp, kp, vT, aout, bits, flags);

  gemm_bt<1><<<dim3(8, 64, 1), 256, 0, stream>>>(aout, nullptr, nullptr, Wob, nullptr, nullptr,
                                                 (void*)d_out, nullptr, nullptr);
}